// Round 1
// baseline (1023.780 us; speedup 1.0000x reference)
//
#include <hip/hip_runtime.h>

#define N_PTS_MAX 800000
#define NC   512      // BATCH(8) * 8 * 8
#define INC  32
#define HID  64
#define OUTC 32

__device__ __forceinline__ int cluster_of(float cx, float cy, int b){
    int ix = (int)(cx * 8.0f); ix = ix < 0 ? 0 : (ix > 7 ? 7 : ix);
    int iy = (int)(cy * 8.0f); iy = iy < 0 ? 0 : (iy > 7 ? 7 : iy);
    return (b << 6) + (iy << 3) + ix;
}

__device__ __forceinline__ float gelu_f(float v){
    return 0.5f * v * (1.0f + erff(v * 0.70710678118654752f));
}

// ---------------- K1: cluster id + histogram ----------------
__global__ void k_hist(const float* __restrict__ sc, const int* __restrict__ sb,
                       int* __restrict__ src_cl, int* __restrict__ cnt, int n){
    int i = blockIdx.x * 256 + threadIdx.x;
    if (i >= n) return;
    int cl = cluster_of(sc[2*i], sc[2*i+1], sb[i]);
    src_cl[i] = cl;
    atomicAdd(&cnt[cl], 1);
}

// ---------------- K2: exclusive scan over 512 counters ----------------
__global__ void k_scan(const int* __restrict__ cnt, int* __restrict__ offs,
                       int* __restrict__ cursor){
    __shared__ int tmp[NC];
    int t = threadIdx.x;
    int v0 = cnt[t];
    tmp[t] = v0;
    __syncthreads();
    for (int d = 1; d < NC; d <<= 1){
        int v = (t >= d) ? tmp[t - d] : 0;
        __syncthreads();
        tmp[t] += v;
        __syncthreads();
    }
    int excl = tmp[t] - v0;
    offs[t] = excl;
    cursor[t] = excl;
}

// ---------------- K3: scatter point indices grouped by cluster ----------------
__global__ void k_scatter(const int* __restrict__ src_cl, int* __restrict__ cursor,
                          int* __restrict__ order, int n){
    int i = blockIdx.x * 256 + threadIdx.x;
    if (i >= n) return;
    int pos = atomicAdd(&cursor[src_cl[i]], 1);
    order[pos] = i;
}

// ---------------- K4: MLP layer-1 + GELU + per-cluster sum of gelu(h1) ----------------
// sum_g[c][64] = sum over points in cluster c of gelu(x @ Wv1 + bv1)
__global__ __launch_bounds__(256) void k_mlp1g_pool(
    const float* __restrict__ x, const int* __restrict__ order,
    const int* __restrict__ offs, const int* __restrict__ cnt,
    const float* __restrict__ Wv1, const float* __restrict__ bv1,
    float* __restrict__ sum_g)
{
    __shared__ __align__(16) float sW1[INC*HID];
    __shared__ float sB1[HID];
    __shared__ float psum[HID];
    const int t = threadIdx.x, c = blockIdx.x;
    for (int k = t; k < INC*HID; k += 256) sW1[k] = Wv1[k];
    if (t < HID){ sB1[t] = bv1[t]; psum[t] = 0.0f; }
    __syncthreads();

    float sum[HID];
    #pragma unroll
    for (int j = 0; j < HID; j++) sum[j] = 0.0f;

    const int beg = offs[c];
    const int n   = cnt[c];
    for (int p = beg + t; p < beg + n; p += 256){
        const int idx = order[p];
        float xv[INC];
        const float4* xr = (const float4*)(x + (size_t)idx * INC);
        #pragma unroll
        for (int q = 0; q < INC/4; q++){
            float4 v = xr[q];
            xv[4*q+0] = v.x; xv[4*q+1] = v.y; xv[4*q+2] = v.z; xv[4*q+3] = v.w;
        }
        // two j-halves of 32 to cap register pressure
        #pragma unroll
        for (int half = 0; half < 2; half++){
            float h[32];
            #pragma unroll
            for (int j = 0; j < 32; j++) h[j] = sB1[half*32 + j];
            #pragma unroll 4
            for (int i = 0; i < INC; i++){
                const float xi = xv[i];
                const float4* wr = (const float4*)(sW1 + i*HID + half*32);
                #pragma unroll
                for (int q = 0; q < 8; q++){
                    float4 w = wr[q];
                    h[4*q+0] += xi * w.x;
                    h[4*q+1] += xi * w.y;
                    h[4*q+2] += xi * w.z;
                    h[4*q+3] += xi * w.w;
                }
            }
            #pragma unroll
            for (int j = 0; j < 32; j++) sum[half*32 + j] += gelu_f(h[j]);
        }
    }

    // block reduction: wave shuffle-reduce, then one LDS atomic per wave
    const int lane = t & 63;
    #pragma unroll
    for (int j = 0; j < HID; j++){
        float v = sum[j];
        #pragma unroll
        for (int s = 32; s > 0; s >>= 1) v += __shfl_xor(v, s, 64);
        if (lane == 0) atomicAdd(&psum[j], v);
    }
    __syncthreads();
    if (t < HID) sum_g[c*HID + t] = psum[t];
}

// ---------------- K5: per-cluster tail:  meang -> @Wv2+bv2 -> @Wt1[2:]+bt1 -> z ----------------
__global__ void k_cluster(const float* __restrict__ sum_g, const int* __restrict__ cnt,
                          const float* __restrict__ Wv2, const float* __restrict__ bv2,
                          const float* __restrict__ Wt1, const float* __restrict__ bt1,
                          float* __restrict__ z)
{
    __shared__ float m[HID];
    __shared__ float ph[HID];
    const int c = blockIdx.x, j = threadIdx.x;  // 64 threads
    const int n = cnt[c];
    const float inv = (n > 0) ? (1.0f / (float)n) : 0.0f;
    m[j] = sum_g[c*HID + j] * inv;
    __syncthreads();
    float a = bv2[j];
    #pragma unroll 8
    for (int i = 0; i < HID; i++) a += m[i] * Wv2[i*HID + j];
    if (n == 0) a = 0.0f;   // reference: pooled = 0 for empty cluster
    ph[j] = a;
    __syncthreads();
    float b = bt1[j];
    #pragma unroll 8
    for (int i = 0; i < HID; i++) b += ph[i] * Wt1[(2 + i)*HID + j];
    z[c*HID + j] = b;
}

// ---------------- K6: per-target-point:  gelu(z[cl] + cx*Wt1[0] + cy*Wt1[1]) @ Wt2 + bt2 ----------------
__global__ __launch_bounds__(256) void k_tgt(
    const float* __restrict__ tc, const int* __restrict__ tb,
    const float* __restrict__ z, const float* __restrict__ Wt1,
    const float* __restrict__ Wt2, const float* __restrict__ bt2,
    float* __restrict__ out, int n)
{
    __shared__ __align__(16) float sW2[HID*OUTC];
    __shared__ float sR0[HID], sR1[HID], sB[OUTC];
    const int t = threadIdx.x;
    for (int k = t; k < HID*OUTC; k += 256) sW2[k] = Wt2[k];
    if (t < HID){ sR0[t] = Wt1[t]; sR1[t] = Wt1[HID + t]; }
    if (t < OUTC) sB[t] = bt2[t];
    __syncthreads();

    const int i = blockIdx.x * 256 + t;
    if (i >= n) return;
    const float cx = tc[2*i], cy = tc[2*i+1];
    const int cl = cluster_of(cx, cy, tb[i]);

    float g[HID];
    const float4* zr = (const float4*)(z + cl*HID);
    #pragma unroll
    for (int q = 0; q < HID/4; q++){
        float4 v = zr[q];
        g[4*q+0] = v.x; g[4*q+1] = v.y; g[4*q+2] = v.z; g[4*q+3] = v.w;
    }
    #pragma unroll
    for (int j = 0; j < HID; j++){
        float pre = g[j] + cx * sR0[j] + cy * sR1[j];
        g[j] = gelu_f(pre);
    }
    float acc[OUTC];
    #pragma unroll
    for (int o = 0; o < OUTC; o++) acc[o] = sB[o];
    #pragma unroll 4
    for (int j = 0; j < HID; j++){
        const float gj = g[j];
        const float4* wr = (const float4*)(sW2 + j*OUTC);
        #pragma unroll
        for (int q = 0; q < OUTC/4; q++){
            float4 w = wr[q];
            acc[4*q+0] += gj * w.x;
            acc[4*q+1] += gj * w.y;
            acc[4*q+2] += gj * w.z;
            acc[4*q+3] += gj * w.w;
        }
    }
    float4* orow = (float4*)(out + (size_t)i * OUTC);
    #pragma unroll
    for (int q = 0; q < OUTC/4; q++){
        orow[q] = make_float4(acc[4*q+0], acc[4*q+1], acc[4*q+2], acc[4*q+3]);
    }
}

extern "C" void kernel_launch(void* const* d_in, const int* in_sizes, int n_in,
                              void* d_out, int out_size, void* d_ws, size_t ws_size,
                              hipStream_t stream)
{
    const float* x   = (const float*)d_in[0];
    const float* sc  = (const float*)d_in[1];
    const int*   sb  = (const int*)  d_in[2];
    const float* tc  = (const float*)d_in[3];
    const int*   tb  = (const int*)  d_in[4];
    const float* Wv1 = (const float*)d_in[5];
    const float* bv1 = (const float*)d_in[6];
    const float* Wv2 = (const float*)d_in[7];
    const float* bv2 = (const float*)d_in[8];
    const float* Wt1 = (const float*)d_in[9];
    const float* bt1 = (const float*)d_in[10];
    const float* Wt2 = (const float*)d_in[11];
    const float* bt2 = (const float*)d_in[12];
    float* out = (float*)d_out;

    const int n = in_sizes[2];   // number of points (src == tgt count here)

    char* ws = (char*)d_ws;
    int*   cnt    = (int*)(ws);                       // 512*4
    int*   offs   = (int*)(ws + 2048);                // 512*4
    int*   cursor = (int*)(ws + 4096);                // 512*4
    float* sum_g  = (float*)(ws + 6144);              // 512*64*4 = 128KB
    float* z      = (float*)(ws + 6144 + 131072);     // 512*64*4 = 128KB
    int*   src_cl = (int*)(ws + 6144 + 262144);       // n*4
    int*   order  = src_cl + n;                       // n*4

    hipMemsetAsync(cnt, 0, NC * sizeof(int), stream);

    const int nb = (n + 255) / 256;
    k_hist   <<<nb, 256, 0, stream>>>(sc, sb, src_cl, cnt, n);
    k_scan   <<<1, NC, 0, stream>>>(cnt, offs, cursor);
    k_scatter<<<nb, 256, 0, stream>>>(src_cl, cursor, order, n);
    k_mlp1g_pool<<<NC, 256, 0, stream>>>(x, order, offs, cnt, Wv1, bv1, sum_g);
    k_cluster<<<NC, HID, 0, stream>>>(sum_g, cnt, Wv2, bv2, Wt1, bt1, z);
    k_tgt    <<<nb, 256, 0, stream>>>(tc, tb, z, Wt1, Wt2, bt2, out, n);
}

// Round 2
// 601.428 us; speedup vs baseline: 1.7022x; 1.7022x over previous
//
#include <hip/hip_runtime.h>

#define NC   512      // BATCH(8) * 8 * 8
#define INC  32
#define HID  64
#define OUTC 32
#define BPB  100      // blocks per batch in k_src

__device__ __forceinline__ float gelu_f(float v){
    return 0.5f * v * (1.0f + erff(v * 0.70710678118654752f));
}

// ---------------- K1: fused MLP layer-1 + GELU + per-cluster pooling ----------------
// Each block handles a contiguous slice of ONE batch sample's points (src_batch is
// repeat(arange(8), PTS), so batch id = blockIdx.x / BPB). Accumulate gelu(x@Wv1+b1)
// into a 64-cluster x 64-channel LDS tile (padded stride 66 to spread LDS-atomic
// banks), then flush to global sum_g with one atomicAdd per tile element.
__global__ __launch_bounds__(256) void k_src(
    const float* __restrict__ x, const float* __restrict__ sc,
    const float* __restrict__ Wv1, const float* __restrict__ bv1,
    float* __restrict__ sum_g, float* __restrict__ gcnt,
    int npb, int ppb)
{
    __shared__ __align__(16) float sW1[INC*HID];
    __shared__ float sB1[HID];
    __shared__ float acc[64*66];
    __shared__ float cntl[64];
    const int t = threadIdx.x;
    const int batch = blockIdx.x / BPB;
    const int pb    = blockIdx.x % BPB;

    for (int k = t; k < INC*HID; k += 256) sW1[k] = Wv1[k];
    if (t < HID) sB1[t] = bv1[t];
    for (int k = t; k < 64*66; k += 256) acc[k] = 0.0f;
    if (t < 64) cntl[t] = 0.0f;
    __syncthreads();

    const int base = batch * npb;
    const int s0 = pb * ppb;
    const int s1 = (s0 + ppb < npb) ? (s0 + ppb) : npb;

    for (int p = s0 + t; p < s1; p += 256){
        const int i = base + p;
        const float cx = sc[2*i], cy = sc[2*i+1];
        int ix = (int)(cx * 8.0f); ix = ix < 0 ? 0 : (ix > 7 ? 7 : ix);
        int iy = (int)(cy * 8.0f); iy = iy < 0 ? 0 : (iy > 7 ? 7 : iy);
        const int lc = (iy << 3) + ix;   // local cluster within batch

        float xv[INC];
        const float4* xr = (const float4*)(x + (size_t)i * INC);
        #pragma unroll
        for (int q = 0; q < INC/4; q++){
            float4 v = xr[q];
            xv[4*q+0] = v.x; xv[4*q+1] = v.y; xv[4*q+2] = v.z; xv[4*q+3] = v.w;
        }
        #pragma unroll
        for (int half = 0; half < 2; half++){
            float h[32];
            #pragma unroll
            for (int j = 0; j < 32; j++) h[j] = sB1[half*32 + j];
            #pragma unroll 4
            for (int ii = 0; ii < INC; ii++){
                const float xi = xv[ii];
                const float4* wr = (const float4*)(sW1 + ii*HID + half*32);
                #pragma unroll
                for (int q = 0; q < 8; q++){
                    float4 w = wr[q];
                    h[4*q+0] += xi * w.x;
                    h[4*q+1] += xi * w.y;
                    h[4*q+2] += xi * w.z;
                    h[4*q+3] += xi * w.w;
                }
            }
            #pragma unroll
            for (int j = 0; j < 32; j++)
                atomicAdd(&acc[lc*66 + half*32 + j], gelu_f(h[j]));
        }
        atomicAdd(&cntl[lc], 1.0f);
    }
    __syncthreads();

    const int cbase = batch * 64;
    for (int k = t; k < 4096; k += 256){
        const int r = k >> 6, cc = k & 63;
        atomicAdd(&sum_g[(cbase + r)*64 + cc], acc[r*66 + cc]);
    }
    if (t < 64) atomicAdd(&gcnt[cbase + t], cntl[t]);
}

// ---------------- K2: per-cluster tail: mean -> @Wv2+bv2 -> @Wt1[2:]+bt1 -> z ----------------
__global__ void k_cluster(const float* __restrict__ sum_g, const float* __restrict__ gcnt,
                          const float* __restrict__ Wv2, const float* __restrict__ bv2,
                          const float* __restrict__ Wt1, const float* __restrict__ bt1,
                          float* __restrict__ z)
{
    __shared__ float m[HID];
    __shared__ float ph[HID];
    const int c = blockIdx.x, j = threadIdx.x;  // 64 threads
    const float nf = gcnt[c];
    const float inv = (nf > 0.0f) ? (1.0f / nf) : 0.0f;
    m[j] = sum_g[c*HID + j] * inv;
    __syncthreads();
    float a = bv2[j];
    #pragma unroll 8
    for (int i = 0; i < HID; i++) a += m[i] * Wv2[i*HID + j];
    if (nf <= 0.0f) a = 0.0f;   // reference: pooled = 0 for empty cluster
    ph[j] = a;
    __syncthreads();
    float b = bt1[j];
    #pragma unroll 8
    for (int i = 0; i < HID; i++) b += ph[i] * Wt1[(2 + i)*HID + j];
    z[c*HID + j] = b;
}

// ---------------- K3: per-target-point: gelu(z[cl] + cx*Wt1[0] + cy*Wt1[1]) @ Wt2 + bt2 ----------------
__global__ __launch_bounds__(256) void k_tgt(
    const float* __restrict__ tc, const int* __restrict__ tb,
    const float* __restrict__ z, const float* __restrict__ Wt1,
    const float* __restrict__ Wt2, const float* __restrict__ bt2,
    float* __restrict__ out, int n)
{
    __shared__ __align__(16) float sW2[HID*OUTC];
    __shared__ float sR0[HID], sR1[HID], sB[OUTC];
    const int t = threadIdx.x;
    for (int k = t; k < HID*OUTC; k += 256) sW2[k] = Wt2[k];
    if (t < HID){ sR0[t] = Wt1[t]; sR1[t] = Wt1[HID + t]; }
    if (t < OUTC) sB[t] = bt2[t];
    __syncthreads();

    const int i = blockIdx.x * 256 + t;
    if (i >= n) return;
    const float cx = tc[2*i], cy = tc[2*i+1];
    int ix = (int)(cx * 8.0f); ix = ix < 0 ? 0 : (ix > 7 ? 7 : ix);
    int iy = (int)(cy * 8.0f); iy = iy < 0 ? 0 : (iy > 7 ? 7 : iy);
    const int cl = (tb[i] << 6) + (iy << 3) + ix;

    float g[HID];
    const float4* zr = (const float4*)(z + cl*HID);
    #pragma unroll
    for (int q = 0; q < HID/4; q++){
        float4 v = zr[q];
        g[4*q+0] = v.x; g[4*q+1] = v.y; g[4*q+2] = v.z; g[4*q+3] = v.w;
    }
    #pragma unroll
    for (int j = 0; j < HID; j++){
        float pre = g[j] + cx * sR0[j] + cy * sR1[j];
        g[j] = gelu_f(pre);
    }
    float acc[OUTC];
    #pragma unroll
    for (int o = 0; o < OUTC; o++) acc[o] = sB[o];
    #pragma unroll 4
    for (int j = 0; j < HID; j++){
        const float gj = g[j];
        const float4* wr = (const float4*)(sW2 + j*OUTC);
        #pragma unroll
        for (int q = 0; q < OUTC/4; q++){
            float4 w = wr[q];
            acc[4*q+0] += gj * w.x;
            acc[4*q+1] += gj * w.y;
            acc[4*q+2] += gj * w.z;
            acc[4*q+3] += gj * w.w;
        }
    }
    float4* orow = (float4*)(out + (size_t)i * OUTC);
    #pragma unroll
    for (int q = 0; q < OUTC/4; q++){
        orow[q] = make_float4(acc[4*q+0], acc[4*q+1], acc[4*q+2], acc[4*q+3]);
    }
}

extern "C" void kernel_launch(void* const* d_in, const int* in_sizes, int n_in,
                              void* d_out, int out_size, void* d_ws, size_t ws_size,
                              hipStream_t stream)
{
    const float* x   = (const float*)d_in[0];
    const float* sc  = (const float*)d_in[1];
    const int*   sb  = (const int*)  d_in[2];  (void)sb;
    const float* tc  = (const float*)d_in[3];
    const int*   tb  = (const int*)  d_in[4];
    const float* Wv1 = (const float*)d_in[5];
    const float* bv1 = (const float*)d_in[6];
    const float* Wv2 = (const float*)d_in[7];
    const float* bv2 = (const float*)d_in[8];
    const float* Wt1 = (const float*)d_in[9];
    const float* bt1 = (const float*)d_in[10];
    const float* Wt2 = (const float*)d_in[11];
    const float* bt2 = (const float*)d_in[12];
    float* out = (float*)d_out;

    const int n   = in_sizes[2];     // total points
    const int npb = n / 8;           // points per batch sample (src_batch = repeat)
    const int ppb = (npb + BPB - 1) / BPB;

    char* ws = (char*)d_ws;
    float* sum_g = (float*)(ws);                         // 512*64*4 = 128KB
    float* gcnt  = (float*)(ws + NC*HID*4);              // 512*4
    float* z     = (float*)(ws + NC*HID*4 + NC*4);       // 512*64*4 = 128KB

    hipMemsetAsync(sum_g, 0, (NC*HID + NC) * sizeof(float), stream);

    k_src    <<<8*BPB, 256, 0, stream>>>(x, sc, Wv1, bv1, sum_g, gcnt, npb, ppb);
    k_cluster<<<NC, HID, 0, stream>>>(sum_g, gcnt, Wv2, bv2, Wt1, bt1, z);
    k_tgt    <<<(n + 255)/256, 256, 0, stream>>>(tc, tb, z, Wt1, Wt2, bt2, out, n);
}